// Round 1
// baseline (4792.128 us; speedup 1.0000x reference)
//
#include <hip/hip_runtime.h>
#include <cstdint>
#include <cstddef>
#include <cmath>

#define H  2048
#define BB 2048   // batch
#define TT 64     // time steps
#define NC 10     // classes

typedef __bf16 bf16;
typedef bf16  bf16x8 __attribute__((ext_vector_type(8)));
typedef float f32x4  __attribute__((ext_vector_type(4)));

// ---------------------------------------------------------------------------
// W_hh fp32 -> bf16, shuffled into MFMA-B-frag-major layout (unchanged):
// subtile (n16, k32) = 16 n-rows x 32 k, 1024 B, at id = n16*64 + k32.
// Within a subtile, lane-slot l (16 B) holds
//   W[n16*16 + (l&15)][k32*32 + (l>>4)*8 .. +8]
// = the v_mfma_f32_16x16x32_bf16 B fragment, so a wave's B-frag load is ONE
// coalesced 1 KB segment: Wshuf + id*512 + lane*8 (bf16 elems).
// ---------------------------------------------------------------------------
__global__ void w_shuffle_kernel(const float* __restrict__ Whh,
                                 bf16* __restrict__ Wshuf) {
    int tid = blockIdx.x * blockDim.x + threadIdx.x;   // 0 .. H*H/8-1
    int sub = tid >> 6;          // subtile id
    int l   = tid & 63;          // dest lane slot
    int n16 = sub >> 6;          // 0..127
    int k32 = sub & 63;          // 0..63
    int n = n16 * 16 + (l & 15);
    int k = k32 * 32 + (l >> 4) * 8;
    const float* src = Whh + (size_t)n * H + k;
    bf16x8 o;
#pragma unroll
    for (int j = 0; j < 8; ++j) o[j] = (bf16)src[j];
    *(bf16x8*)(Wshuf + (size_t)tid * 8) = o;
}

// ---------------------------------------------------------------------------
// t = 0: S[b,i] = tanh(Whx[i]*x[b,0] + bh[i]).  One block per batch row.
// ---------------------------------------------------------------------------
__global__ void rnn_init(const float* __restrict__ x,     // [B, T]
                         const float* __restrict__ Whx,   // [H]
                         const float* __restrict__ bh,    // [H]
                         bf16* __restrict__ S) {          // [B, H]
    int b  = blockIdx.x;
    int i0 = threadIdx.x * 8;
    float xv = x[(size_t)b * TT];
    bf16x8 o;
#pragma unroll
    for (int j = 0; j < 8; ++j)
        o[j] = (bf16)tanhf(Whx[i0 + j] * xv + bh[i0 + j]);
    *(bf16x8*)(S + (size_t)b * H + i0) = o;
}

// ---------------------------------------------------------------------------
// One RNN time step, Round-11 "reg-direct" structure:
//   Sw[b,i] = tanh( sum_k Sr[b,k]*W[i,k] + Whx[i]*x[b,t] + bh[i] )
//
// Diagnosis of R10: per-CU/step LDS traffic (3 MB = ~11.6 us) and L2 traffic
// (~1 MB+dup = 11-15 us) both exceed the MFMA floor (8.3 us); 32 barrier
// drains/step on top. The LDS staging is PURE overhead in this decomposition:
// A-frags are register-cached across fn already, and no two waves ever read
// the same (rows,k) of A -> no cross-wave reuse to justify the round-trip.
//
// New structure:
//   - 128x128 block tiles, grid 256 = 1 block/CU (no tail), 512 thr / 8 waves.
//     Bigger n-tile halves chip-level A duplication (32 -> 16 n-tiles).
//   - Wave (ms, ns) owns a 64x32 sub-tile, walks the FULL K: fm4 x fn2 frags,
//     acc[4][2] f32x4 (32 VGPRs). No cross-wave reduction needed.
//   - A and B fragments load DIRECTLY global->VGPR, double-buffered per
//     64-k chunk. Zero LDS, zero __syncthreads in the K-loop, so no
//     vmcnt(0)-drain stalls; the compiler emits precise counted waitcnts for
//     pure register dependencies.
//   - A-frag instr = 16 rows x 64B (kc pair covers each row's full 128B line);
//     B-frag = 1 KB contiguous (frag-major Wshuf). Raw s_barrier per chunk
//     (rendezvous only, NO waitcnt semantics) keeps the 8 waves chunk-locked
//     so the x4 A-twin / x2 B-twin reads merge in the shared per-CU L1/MSHRs.
//     Unique L2->CU traffic: (A 16KB + B 16KB)/chunk x 32 = 1 MB/CU/step
//     = 7.8 us < MFMA 8.3 us -> compute-bound.
//   - Same fm/fn/lane fragment math and f32 accumulation order as the
//     verified R10 kernel -> bit-identical numerics.
// ---------------------------------------------------------------------------
__launch_bounds__(512, 2)
__global__ void rnn_step(const float* __restrict__ x,     // [B, T]
                         const float* __restrict__ Whx,   // [H]
                         const float* __restrict__ bh,    // [H]
                         const bf16*  __restrict__ Wshuf, // [H, H] frag-major
                         const bf16*  __restrict__ Sr,    // [B, H] read
                         bf16* __restrict__ Sw,           // [B, H] write
                         int t) {
    const int tid  = threadIdx.x;
    const int w    = tid >> 6;          // wave 0..7
    const int lane = tid & 63;
    const int lrow = lane & 15;
    const int quad = lane >> 4;

    // XCD-aware mapping: XCD owns batch rows (S producer-consumer locality).
    // 16 m-tiles x 16 n-tiles; 2 m-tiles (256 rows = 1 MB of S) per XCD stay
    // resident in that XCD's L2 across steps.
    const int xcd = blockIdx.x & 7;
    const int loc = blockIdx.x >> 3;               // 0..31
    const int bm0 = (xcd * 2 + (loc & 1)) * 128;   // batch-row tile origin
    const int bn0 = (loc >> 1) * 128;              // hidden-col tile origin

    const int ms = w & 1;      // m sub-tile (64 rows)
    const int ns = w >> 1;     // n sub-tile (32 cols), 0..3

    // A-frag base per fm: row = bm0 + ms*64 + fm*16 + lrow, k-base = quad*8.
    // frag(fm,kc) at chunk c: 16B at pA[fm] + c*64 + kc*32  (bf16 elems)
    const bf16* pA[4];
#pragma unroll
    for (int fm = 0; fm < 4; ++fm)
        pA[fm] = Sr + (size_t)(bm0 + ms * 64 + fm * 16 + lrow) * H + quad * 8;

    // B-frag base per fn: subtile n16 = (bn0 + ns*32)/16 + fn.
    // frag(fn,kc) at chunk c: 16B at pB[fn] + (c*2 + kc)*512  (bf16 elems)
    const bf16* pB[2];
#pragma unroll
    for (int fn = 0; fn < 2; ++fn)
        pB[fn] = Wshuf + ((size_t)(((bn0 + ns * 32) >> 4) + fn) * 64) * 512
                       + (size_t)lane * 8;

    f32x4 acc[4][2];
#pragma unroll
    for (int i = 0; i < 4; ++i)
#pragma unroll
        for (int j = 0; j < 2; ++j) acc[i][j] = (f32x4){0.f, 0.f, 0.f, 0.f};

    auto loadA = [&](bf16x8 (&Af)[8], int c) {
#pragma unroll
        for (int kc = 0; kc < 2; ++kc)
#pragma unroll
            for (int fm = 0; fm < 4; ++fm)
                Af[kc * 4 + fm] = *(const bf16x8*)(pA[fm] + c * 64 + kc * 32);
    };
    auto loadBf = [&](bf16x8 (&Bf)[4], int c) {
#pragma unroll
        for (int kc = 0; kc < 2; ++kc)
#pragma unroll
            for (int fn = 0; fn < 2; ++fn)
                Bf[kc * 2 + fn] = *(const bf16x8*)(pB[fn] + (c * 2 + kc) * 512);
    };
    auto compute = [&](bf16x8 (&Af)[8], bf16x8 (&Bf)[4]) {
#pragma unroll
        for (int kc = 0; kc < 2; ++kc)
#pragma unroll
            for (int fm = 0; fm < 4; ++fm)
#pragma unroll
                for (int fn = 0; fn < 2; ++fn)
                    acc[fm][fn] = __builtin_amdgcn_mfma_f32_16x16x32_bf16(
                        Af[kc * 4 + fm], Bf[kc * 2 + fn], acc[fm][fn], 0, 0, 0);
    };

    // K-loop: 32 chunks of 64k, ping-pong register double-buffer, barrier-free
    // except the raw pacing s_barrier (keeps twin loads L1-coincident).
    bf16x8 A0[8], A1[8], B0f[4], B1f[4];
    loadA(A0, 0);
    loadBf(B0f, 0);
#pragma unroll 1
    for (int c = 0; c < 32; c += 2) {
        loadA(A1, c + 1);                  // c+1 <= 31 always
        loadBf(B1f, c + 1);
        __builtin_amdgcn_s_barrier();      // pacing only — no waitcnt drain
        compute(A0, B0f);
        if (c + 2 < 32) { loadA(A0, c + 2); loadBf(B0f, c + 2); }
        __builtin_amdgcn_s_barrier();
        compute(A1, B1f);
    }

    // epilogue: z += Whx[i]*x[b,t] + bh[i]; tanh; store bf16.
    // C layout (16x16x32): col = lane&15, row = quad*4 + reg  [m89-verified]
#pragma unroll
    for (int fm = 0; fm < 4; ++fm) {
        int rb = bm0 + ms * 64 + fm * 16 + quad * 4;
        float xv[4];
#pragma unroll
        for (int r = 0; r < 4; ++r) xv[r] = x[(size_t)(rb + r) * TT + t];
#pragma unroll
        for (int fn = 0; fn < 2; ++fn) {
            int col = bn0 + ns * 32 + fn * 16 + lrow;
            float wx = Whx[col], bb = bh[col];
#pragma unroll
            for (int r = 0; r < 4; ++r) {
                float z = acc[fm][fn][r] + wx * xv[r] + bb;
                Sw[(size_t)(rb + r) * H + col] = (bf16)tanhf(z);
            }
        }
    }
}

// ---------------------------------------------------------------------------
// out[b,c] = sum_h Why[h,c] * S[b,h] + bp[c]   (S = h_T^T, [B,H] bf16)
// one block per batch row
// ---------------------------------------------------------------------------
__global__ void out_proj(const bf16* __restrict__ S,
                         const float* __restrict__ Why,   // [H, C]
                         const float* __restrict__ bp,    // [C]
                         float* __restrict__ out) {       // [B, C]
    int b = blockIdx.x, tid = threadIdx.x;
    float p[NC];
#pragma unroll
    for (int c = 0; c < NC; ++c) p[c] = 0.f;
    for (int h = tid; h < H; h += 256) {
        float s = (float)S[(size_t)b * H + h];
        const float* wr = Why + h * NC;
#pragma unroll
        for (int c = 0; c < NC; ++c) p[c] += s * wr[c];
    }
    __shared__ float red[256 * NC];
#pragma unroll
    for (int c = 0; c < NC; ++c) red[tid * NC + c] = p[c];
    __syncthreads();
    for (int s = 128; s > 0; s >>= 1) {
        if (tid < s)
#pragma unroll
            for (int c = 0; c < NC; ++c) red[tid * NC + c] += red[(tid + s) * NC + c];
        __syncthreads();
    }
    if (tid < NC) out[(size_t)b * NC + tid] = red[tid] + bp[tid];
}

// ---------------------------------------------------------------------------
extern "C" void kernel_launch(void* const* d_in, const int* in_sizes, int n_in,
                              void* d_out, int out_size, void* d_ws, size_t ws_size,
                              hipStream_t stream) {
    const float* x   = (const float*)d_in[0];   // [B, T]
    const float* Whx = (const float*)d_in[1];   // [H, 1]
    const float* Whh = (const float*)d_in[2];   // [H, H]
    const float* Why = (const float*)d_in[3];   // [H, C]
    const float* bh  = (const float*)d_in[4];   // [H, 1]
    const float* bp  = (const float*)d_in[5];   // [C, 1]
    float* out = (float*)d_out;

    // workspace: Wshuf (8 MB) | S0 (8 MB) | S1 (8 MB)
    bf16* Wshuf = (bf16*)d_ws;
    bf16* S0 = (bf16*)((char*)d_ws + (size_t)8 * 1024 * 1024);
    bf16* S1 = (bf16*)((char*)d_ws + (size_t)16 * 1024 * 1024);

    hipLaunchKernelGGL(w_shuffle_kernel, dim3((H * H / 8) / 256), dim3(256),
                       0, stream, Whh, Wshuf);

    // t = 0 writes S1; step t reads (t&1 ? S1 : S0), writes the other.
    hipLaunchKernelGGL(rnn_init, dim3(BB), dim3(256), 0, stream, x, Whx, bh, S1);

    for (int t = 1; t < TT; ++t) {
        const bf16* Srd = (t & 1) ? S1 : S0;
        bf16*       Swr = (t & 1) ? S0 : S1;
        hipLaunchKernelGGL(rnn_step, dim3(256), dim3(512), 0, stream,
                           x, Whx, bh, Wshuf, Srd, Swr, t);
    }

    // t=63 (odd) wrote S0
    hipLaunchKernelGGL(out_proj, dim3(BB), dim3(256), 0, stream, S0, Why, bp, out);
}

// Round 2
// 2041.998 us; speedup vs baseline: 2.3468x; 2.3468x over previous
//
#include <hip/hip_runtime.h>
#include <cstdint>
#include <cstddef>
#include <cmath>

#define H  2048
#define BB 2048   // batch
#define TT 64     // time steps
#define NC 10     // classes

typedef __bf16 bf16;
typedef bf16  bf16x8 __attribute__((ext_vector_type(8)));
typedef float f32x4  __attribute__((ext_vector_type(4)));

// ---------------------------------------------------------------------------
// FRAG-MAJOR layout (both operands use the same scheme).
// For a matrix [R rows][H k-cols] (bf16):
//   subtile (r16, k32) = 16 rows x 32 k = 1024 B at id = r16*(H/32) + k32.
//   lane-slot l (16 B) holds M[r16*16 + (l&15)][k32*32 + (l>>4)*8 .. +8]
// = exactly the v_mfma_f32_16x16x32_bf16 A- or B-operand fragment, so a
// wave's frag load is ONE coalesced 1 KB segment: base + id*512 + lane*8.
// Wshuf (W_hh, n-major) has used this since R10.  NEW in R12: S itself is
// stored frag-major (the step epilogue emits it), so A-loads are identical
// coalesced streams and the K-loop needs NO LDS and NO barriers-with-drain.
// ---------------------------------------------------------------------------
__global__ void w_shuffle_kernel(const float* __restrict__ Whh,
                                 bf16* __restrict__ Wshuf) {
    int tid = blockIdx.x * blockDim.x + threadIdx.x;   // 0 .. H*H/8-1
    int sub = tid >> 6;          // subtile id
    int l   = tid & 63;          // dest lane slot
    int n16 = sub >> 6;          // 0..127
    int k32 = sub & 63;          // 0..63
    int n = n16 * 16 + (l & 15);
    int k = k32 * 32 + (l >> 4) * 8;
    const float* src = Whh + (size_t)n * H + k;
    bf16x8 o;
#pragma unroll
    for (int j = 0; j < 8; ++j) o[j] = (bf16)src[j];
    *(bf16x8*)(Wshuf + (size_t)tid * 8) = o;
}

// ---------------------------------------------------------------------------
// t = 0: S[b,i] = tanh(Whx[i]*x[b,0] + bh[i]), written FRAG-MAJOR.
// thread covers 8 consecutive i = one 16B lane-slot exactly.
// ---------------------------------------------------------------------------
__global__ void rnn_init(const float* __restrict__ x,     // [B, T]
                         const float* __restrict__ Whx,   // [H]
                         const float* __restrict__ bh,    // [H]
                         bf16* __restrict__ S) {          // frag-major
    int b  = blockIdx.x;
    int i0 = threadIdx.x * 8;
    float xv = x[(size_t)b * TT];
    bf16x8 o;
#pragma unroll
    for (int j = 0; j < 8; ++j)
        o[j] = (bf16)tanhf(Whx[i0 + j] * xv + bh[i0 + j]);
    size_t sub  = (size_t)(b >> 4) * 64 + (i0 >> 5);
    size_t slot = (size_t)(b & 15) | (size_t)(((i0 >> 3) & 3) << 4);
    *(bf16x8*)(S + (sub * 64 + slot) * 8) = o;
}

// ---------------------------------------------------------------------------
// One RNN time step, Round-12 "dual-frag-major, zero-LDS K-loop":
//   Sw[b,i] = tanh( sum_k Sr[b,k]*W[i,k] + Whx[i]*x[b,t] + bh[i] )
//
// R11 post-mortem: reg-direct failed from (a) 16-segment scattered A-loads,
// (b) depth-1 prefetch vs L2/L3 latency. R10's B-path (frag-major 1KB
// coalesced reg-loads) was always fine. Fix: make A look like B.
//
//   - S stored FRAG-MAJOR (epilogue of this kernel emits it): every operand
//     load is a single coalesced 1 KB wave-stream. No LDS round-trip for A
//     (removes ~1.5 MB/CU/step of LDS traffic = the largest R10 term), no
//     vmcnt(0)-draining __syncthreads in the K-loop at all.
//   - 128x128 tile, grid 256 = 1 block/CU (zero tail), 512 thr / 8 waves,
//     wave tile 32(m) x 64(n) [qm = w&3, qn = w>>2]. Chip traffic/step =
//     8MB*(16+16) = 256 MB -> 1 MB/CU ~ 7.8 us of L2 time vs 8.3 us MFMA
//     floor: balanced, and S-tiles are XCD-local (m-mapping) = L2-hit.
//   - K-loop: 64 chunks of k32, DEPTH-4 register prefetch (4 named buffer
//     sets; ~620 cy slack/wave vs ~300 cy L2-hit latency). Compiler emits
//     precise counted vmcnt for pure reg deps. One raw pacing s_barrier per
//     4 chunks keeps the waves' duplicate A/B lines L1-coincident.
//   - Accumulation order (k32 ascending, one 16x16x32 MFMA per chunk per
//     acc) is identical to R10 -> bit-identical GEMM numerics.
//   - Epilogue: tanh in regs, 4KB/wave XOR-swizzled LDS transpose, emit
//     Sw frag-major with 16B coalesced stores.
// ---------------------------------------------------------------------------
__launch_bounds__(512, 2)
__global__ void rnn_step(const float* __restrict__ x,     // [B, T]
                         const float* __restrict__ Whx,   // [H]
                         const float* __restrict__ bh,    // [H]
                         const bf16*  __restrict__ Wshuf, // frag-major W_hh
                         const bf16*  __restrict__ Sr,    // frag-major S read
                         bf16* __restrict__ Sw,           // frag-major S write
                         int t) {
    __shared__ bf16 Lt[8 * 2048];       // 8 waves x (32x64 bf16) = 32 KB

    const int tid  = threadIdx.x;
    const int w    = tid >> 6;          // wave 0..7
    const int lane = tid & 63;
    const int lrow = lane & 15;
    const int quad = lane >> 4;

    // XCD-aware: XCD owns batch rows -> S produced AND consumed in-XCD (L2).
    const int xcd = blockIdx.x & 7;
    const int loc = blockIdx.x >> 3;               // 0..31
    const int bm0 = (xcd * 2 + (loc & 1)) * 128;   // batch-row tile origin
    const int bn0 = (loc >> 1) * 128;              // hidden-col tile origin

    const int qm   = w & 3;                        // 4 m-groups x 32 rows
    const int qn   = w >> 2;                       // 2 n-groups x 64 cols
    const int m16w = (bm0 >> 4) + qm * 2;          // wave's first m16 subtile
    const int cn0  = bn0 + qn * 64;                // wave's first col
    const int n16w = cn0 >> 4;                     // wave's first n16 subtile

    const bf16* pA = Sr    + (size_t)lane * 8;
    const bf16* pB = Wshuf + (size_t)lane * 8;

    f32x4 acc[2][4];
#pragma unroll
    for (int i = 0; i < 2; ++i)
#pragma unroll
        for (int j = 0; j < 4; ++j) acc[i][j] = (f32x4){0.f, 0.f, 0.f, 0.f};

    auto LA = [&](bf16x8 (&A)[2], int c) {
#pragma unroll
        for (int fm = 0; fm < 2; ++fm)
            A[fm] = *(const bf16x8*)(pA + (size_t)((m16w + fm) * 64 + c) * 512);
    };
    auto LB = [&](bf16x8 (&Bv)[4], int c) {
#pragma unroll
        for (int fn = 0; fn < 4; ++fn)
            Bv[fn] = *(const bf16x8*)(pB + (size_t)((n16w + fn) * 64 + c) * 512);
    };
    auto CMP = [&](bf16x8 (&A)[2], bf16x8 (&Bv)[4]) {
#pragma unroll
        for (int fm = 0; fm < 2; ++fm)
#pragma unroll
            for (int fn = 0; fn < 4; ++fn)
                acc[fm][fn] = __builtin_amdgcn_mfma_f32_16x16x32_bf16(
                    A[fm], Bv[fn], acc[fm][fn], 0, 0, 0);
    };

    // depth-4 register pipeline over 64 k32-chunks (named bufs: no dynamic
    // indexing -> no scratch, rule #20).
    bf16x8 A0[2], A1[2], A2[2], A3[2];
    bf16x8 B0[4], B1[4], B2[4], B3[4];
    LA(A0, 0); LB(B0, 0); LA(A1, 1); LB(B1, 1);
    LA(A2, 2); LB(B2, 2); LA(A3, 3); LB(B3, 3);

#pragma unroll 1
    for (int c = 0; c < 64; c += 4) {
        __builtin_amdgcn_s_barrier();      // pacing only (no LDS in loop)
        CMP(A0, B0); if (c + 4 < 64) { LA(A0, c + 4); LB(B0, c + 4); }
        CMP(A1, B1); if (c + 5 < 64) { LA(A1, c + 5); LB(B1, c + 5); }
        CMP(A2, B2); if (c + 6 < 64) { LA(A2, c + 6); LB(B2, c + 6); }
        CMP(A3, B3); if (c + 7 < 64) { LA(A3, c + 7); LB(B3, c + 7); }
    }

    // ---- epilogue: z += Whx*x + bh; tanh; transpose to frag-major Sw ----
    // acc layout (16x16x32): col = lane&15, row = quad*4 + reg [m89-verified]
    bf16* Lw = Lt + w * 2048;   // wave-private 32 rows x 128 B, XOR-swizzled
#pragma unroll
    for (int fm = 0; fm < 2; ++fm) {
        int rb = bm0 + qm * 32 + fm * 16 + quad * 4;
        float xv[4];
#pragma unroll
        for (int r = 0; r < 4; ++r) xv[r] = x[(size_t)(rb + r) * TT + t];
#pragma unroll
        for (int fn = 0; fn < 4; ++fn) {
            int col = cn0 + fn * 16 + lrow;
            float wx = Whx[col], bb = bh[col];
            int cbyte = (fn * 16 + lrow) * 2;
#pragma unroll
            for (int r = 0; r < 4; ++r) {
                int row_l = fm * 16 + quad * 4 + r;
                float z = acc[fm][fn][r] + wx * xv[r] + bb;
                *(bf16*)((char*)Lw + row_l * 128 +
                         (cbyte ^ ((row_l & 7) << 4))) = (bf16)tanhf(z);
            }
        }
    }
    __syncthreads();
    // read own wave's tile in frag-slot order; 16B coalesced global stores.
#pragma unroll
    for (int fm = 0; fm < 2; ++fm) {
#pragma unroll
        for (int kc = 0; kc < 2; ++kc) {
            int row_l = fm * 16 + lrow;
            int cb    = (kc * 64 + quad * 16) ^ ((row_l & 7) << 4);
            bf16x8 v = *(const bf16x8*)((const char*)Lw + row_l * 128 + cb);
            size_t sub = (size_t)(m16w + fm) * 64 + (cn0 >> 5) + kc;
            *(bf16x8*)(Sw + (sub * 64 + lane) * 8) = v;
        }
    }
}

// ---------------------------------------------------------------------------
// out[b,c] = sum_h Why[h,c] * S[b,h] + bp[c]   (S frag-major)
// one block per batch row; thread covers 8 consecutive h = one lane-slot.
// ---------------------------------------------------------------------------
__global__ void out_proj(const bf16* __restrict__ S,
                         const float* __restrict__ Why,   // [H, C]
                         const float* __restrict__ bp,    // [C]
                         float* __restrict__ out) {       // [B, C]
    int b = blockIdx.x, tid = threadIdx.x;
    int h0 = tid * 8;                                     // 256*8 = H exactly
    size_t sub  = (size_t)(b >> 4) * 64 + (h0 >> 5);
    size_t slot = (size_t)(b & 15) | (size_t)(((h0 >> 3) & 3) << 4);
    bf16x8 v = *(const bf16x8*)(S + (sub * 64 + slot) * 8);
    float p[NC];
#pragma unroll
    for (int c = 0; c < NC; ++c) p[c] = 0.f;
#pragma unroll
    for (int j = 0; j < 8; ++j) {
        float s = (float)v[j];
        const float* wr = Why + (size_t)(h0 + j) * NC;
#pragma unroll
        for (int c = 0; c < NC; ++c) p[c] += s * wr[c];
    }
    __shared__ float red[256 * NC];
#pragma unroll
    for (int c = 0; c < NC; ++c) red[tid * NC + c] = p[c];
    __syncthreads();
    for (int s = 128; s > 0; s >>= 1) {
        if (tid < s)
#pragma unroll
            for (int c = 0; c < NC; ++c) red[tid * NC + c] += red[(tid + s) * NC + c];
        __syncthreads();
    }
    if (tid < NC) out[(size_t)b * NC + tid] = red[tid] + bp[tid];
}

// ---------------------------------------------------------------------------
extern "C" void kernel_launch(void* const* d_in, const int* in_sizes, int n_in,
                              void* d_out, int out_size, void* d_ws, size_t ws_size,
                              hipStream_t stream) {
    const float* x   = (const float*)d_in[0];   // [B, T]
    const float* Whx = (const float*)d_in[1];   // [H, 1]
    const float* Whh = (const float*)d_in[2];   // [H, H]
    const float* Why = (const float*)d_in[3];   // [H, C]
    const float* bh  = (const float*)d_in[4];   // [H, 1]
    const float* bp  = (const float*)d_in[5];   // [C, 1]
    float* out = (float*)d_out;

    // workspace: Wshuf (8 MB) | S0 (8 MB) | S1 (8 MB)   (all frag-major)
    bf16* Wshuf = (bf16*)d_ws;
    bf16* S0 = (bf16*)((char*)d_ws + (size_t)8 * 1024 * 1024);
    bf16* S1 = (bf16*)((char*)d_ws + (size_t)16 * 1024 * 1024);

    hipLaunchKernelGGL(w_shuffle_kernel, dim3((H * H / 8) / 256), dim3(256),
                       0, stream, Whh, Wshuf);

    // t = 0 writes S1; step t reads (t&1 ? S1 : S0), writes the other.
    hipLaunchKernelGGL(rnn_init, dim3(BB), dim3(256), 0, stream, x, Whx, bh, S1);

    for (int t = 1; t < TT; ++t) {
        const bf16* Srd = (t & 1) ? S1 : S0;
        bf16*       Swr = (t & 1) ? S0 : S1;
        hipLaunchKernelGGL(rnn_step, dim3(256), dim3(512), 0, stream,
                           x, Whx, bh, Wshuf, Srd, Swr, t);
    }

    // t=63 (odd) wrote S0
    hipLaunchKernelGGL(out_proj, dim3(BB), dim3(256), 0, stream, S0, Why, bp, out);
}

// Round 3
// 1745.396 us; speedup vs baseline: 2.7456x; 1.1699x over previous
//
#include <hip/hip_runtime.h>
#include <cstdint>
#include <cstddef>
#include <cmath>

#define H  2048
#define BB 2048   // batch
#define TT 64     // time steps
#define NC 10     // classes

typedef __bf16 bf16;
typedef bf16  bf16x8 __attribute__((ext_vector_type(8)));
typedef float f32x4  __attribute__((ext_vector_type(4)));

// ---------------------------------------------------------------------------
// async global->LDS, 16B per lane. LDS dest is wave-uniform base + lane*16;
// global source is per-lane.
// ---------------------------------------------------------------------------
__device__ __forceinline__ void load_lds16(const void* g, void* l) {
    __builtin_amdgcn_global_load_lds(
        (__attribute__((address_space(1))) void*)(void*)g,
        (__attribute__((address_space(3))) void*)l,
        16, 0, 0);
}

// ---------------------------------------------------------------------------
// FRAG-MAJOR layout (both operands, and S itself since R12).
// For a matrix [R rows][H k-cols] (bf16):
//   subtile (r16, k32) = 16 rows x 32 k = 1024 B at id = r16*(H/32) + k32.
//   lane-slot l (16 B) holds M[r16*16 + (l&15)][k32*32 + (l>>4)*8 .. +8]
// = exactly the v_mfma_f32_16x16x32_bf16 A/B fragment, so a wave's frag load
// is ONE coalesced 1 KB segment: base + id*512 + lane*8 (bf16 elems).
// ---------------------------------------------------------------------------
__global__ void w_shuffle_kernel(const float* __restrict__ Whh,
                                 bf16* __restrict__ Wshuf) {
    int tid = blockIdx.x * blockDim.x + threadIdx.x;   // 0 .. H*H/8-1
    int sub = tid >> 6;          // subtile id
    int l   = tid & 63;          // dest lane slot
    int n16 = sub >> 6;          // 0..127
    int k32 = sub & 63;          // 0..63
    int n = n16 * 16 + (l & 15);
    int k = k32 * 32 + (l >> 4) * 8;
    const float* src = Whh + (size_t)n * H + k;
    bf16x8 o;
#pragma unroll
    for (int j = 0; j < 8; ++j) o[j] = (bf16)src[j];
    *(bf16x8*)(Wshuf + (size_t)tid * 8) = o;
}

// ---------------------------------------------------------------------------
// t = 0: S[b,i] = tanh(Whx[i]*x[b,0] + bh[i]), written FRAG-MAJOR.
// ---------------------------------------------------------------------------
__global__ void rnn_init(const float* __restrict__ x,     // [B, T]
                         const float* __restrict__ Whx,   // [H]
                         const float* __restrict__ bh,    // [H]
                         bf16* __restrict__ S) {          // frag-major
    int b  = blockIdx.x;
    int i0 = threadIdx.x * 8;
    float xv = x[(size_t)b * TT];
    bf16x8 o;
#pragma unroll
    for (int j = 0; j < 8; ++j)
        o[j] = (bf16)tanhf(Whx[i0 + j] * xv + bh[i0 + j]);
    size_t sub  = (size_t)(b >> 4) * 64 + (i0 >> 5);
    size_t slot = (size_t)(b & 15) | (size_t)(((i0 >> 3) & 3) << 4);
    *(bf16x8*)(S + (sub * 64 + slot) * 8) = o;
}

// ---------------------------------------------------------------------------
// One RNN time step, Round-13 "hybrid: LDS-staged B, reg-direct A":
//   Sw[b,i] = tanh( sum_k Sr[b,k]*W[i,k] + Whx[i]*x[b,t] + bh[i] )
//
// R12 post-mortem: zero-sharing reg-direct puts 3 MB/CU/step (A x2 dup +
// B x4 dup) on the VMEM return path ~= 20 us — the wall. Fix: route the
// 4x-duplicated operand (B) through LDS so its duplication costs LDS-read
// bandwidth (separate pipe), keep A (2x dup) on the proven coalesced
// reg-direct path.
//
//   - 128x128 tile, grid 256 = 1 block/CU (zero tail), 512 thr / 8 waves,
//     wave tile 32(m) x 64(n): qm = w&3, qn = w>>2.
//   - B: global_load_lds in groups of 4 k32-chunks (wave w stages subtile
//     n16local=w, 4 segments of 1 KB). Double-buffered 2 x 32 KB. Consumed
//     as ds_read_b128 at lane*16 within a 1 KB segment (conflict-free,
//     frag-major = linear in lane-consumption order; no swizzle needed).
//   - A: frag-major coalesced 1 KB wave-loads, one GROUP (4 chunks x 2 fm)
//     ahead in a reg ping-pong (AE/AO, no dynamic indexing).
//   - ONE __syncthreads per group-half (16/step, was 32 in R10); stage+
//     A-prefetch issue at the TOP of each compute phase, so the barrier's
//     vmcnt(0) drain finds them complete (T14 issue-early/drain-late).
//   - Per-chunk/CU: VMEM 24 KB (~500cy), LDS-read 32 KB (~385cy), MFMA
//     310cy — independent pipes, overlapped by 8 waves.
//   - Accumulation order (k32 ascending, fm->fn) identical to R12 ->
//     bit-identical numerics.
// ---------------------------------------------------------------------------
__launch_bounds__(512, 2)
__global__ void rnn_step(const float* __restrict__ x,     // [B, T]
                         const float* __restrict__ Whx,   // [H]
                         const float* __restrict__ bh,    // [H]
                         const bf16*  __restrict__ Wshuf, // frag-major W_hh
                         const bf16*  __restrict__ Sr,    // frag-major S read
                         bf16* __restrict__ Sw,           // frag-major S write
                         int t) {
    // 2 bufs x 32 segments x 1 KB = 64 KB; epilogue reuses first 32 KB.
    __shared__ __align__(16) bf16 Bs[2][32 * 512];

    const int tid  = threadIdx.x;
    const int w    = tid >> 6;          // wave 0..7
    const int lane = tid & 63;
    const int lrow = lane & 15;
    const int quad = lane >> 4;

    // XCD-aware: XCD owns batch rows -> S produced AND consumed in-XCD (L2).
    const int xcd = blockIdx.x & 7;
    const int loc = blockIdx.x >> 3;               // 0..31
    const int bm0 = (xcd * 2 + (loc & 1)) * 128;   // batch-row tile origin
    const int bn0 = (loc >> 1) * 128;              // hidden-col tile origin

    const int qm   = w & 3;                        // 4 m-groups x 32 rows
    const int qn   = w >> 2;                       // 2 n-groups x 64 cols
    const int m16w = (bm0 >> 4) + qm * 2;          // wave's first m16 subtile
    const int cn0  = bn0 + qn * 64;                // wave's first col
    const int n16b = bn0 >> 4;                     // block's first n16 subtile

    const bf16* pA = Sr + (size_t)lane * 8;
    // stage source: wave w owns subtile (n16b + w); per-lane src = +lane*16B
    const bf16* pSt = Wshuf + ((size_t)(n16b + w) * 64) * 512 + (size_t)lane * 8;

    f32x4 acc[2][4];
#pragma unroll
    for (int i = 0; i < 2; ++i)
#pragma unroll
        for (int j = 0; j < 4; ++j) acc[i][j] = (f32x4){0.f, 0.f, 0.f, 0.f};

    // stage group g (k32 chunks 4g..4g+3) of B into Bs[buf]
    auto stageB = [&](int buf, int g) {
#pragma unroll
        for (int cl = 0; cl < 4; ++cl)
            load_lds16(pSt + (size_t)(4 * g + cl) * 512,
                       &Bs[buf][(w * 4 + cl) * 512]);
    };
    // load group g of A fragments into regs (4 chunks x 2 fm)
    auto loadAg = [&](bf16x8 (&A)[4][2], int g) {
#pragma unroll
        for (int cl = 0; cl < 4; ++cl)
#pragma unroll
            for (int fm = 0; fm < 2; ++fm)
                A[cl][fm] = *(const bf16x8*)(pA +
                    (size_t)((m16w + fm) * 64 + 4 * g + cl) * 512);
    };
    // compute group: 16 ds_read_b128 + 32 MFMA per wave
    auto computeG = [&](int buf, bf16x8 (&A)[4][2]) {
#pragma unroll
        for (int cl = 0; cl < 4; ++cl) {
            bf16x8 Bf[4];
#pragma unroll
            for (int fn = 0; fn < 4; ++fn)
                Bf[fn] = *(const bf16x8*)&Bs[buf]
                    [((qn * 4 + fn) * 4 + cl) * 512 + lane * 8];
#pragma unroll
            for (int fm = 0; fm < 2; ++fm)
#pragma unroll
                for (int fn = 0; fn < 4; ++fn)
                    acc[fm][fn] = __builtin_amdgcn_mfma_f32_16x16x32_bf16(
                        A[cl][fm], Bf[fn], acc[fm][fn], 0, 0, 0);
        }
    };

    bf16x8 AE[4][2], AO[4][2];
    stageB(0, 0);
    loadAg(AE, 0);
    __syncthreads();                       // prologue stage complete

#pragma unroll 1
    for (int j = 0; j < 8; ++j) {          // 16 groups, 2 per iteration
        stageB(1, 2 * j + 1);              // issue-early for next half
        loadAg(AO, 2 * j + 1);
        computeG(0, AE);
        __syncthreads();                   // drain: stage(2j+1) done, Bs[0] free
        if (j < 7) { stageB(0, 2 * j + 2); loadAg(AE, 2 * j + 2); }
        computeG(1, AO);
        __syncthreads();                   // drain: stage(2j+2) done, Bs[1] free
    }

    // ---- epilogue: z += Whx*x + bh; tanh; transpose to frag-major Sw ----
    // acc layout (16x16x32): col = lane&15, row = quad*4 + reg [m89-verified]
    bf16* Lw = &Bs[0][0] + w * 2048;   // wave-private 32 rows x 128 B, swizzled
#pragma unroll
    for (int fm = 0; fm < 2; ++fm) {
        int rb = bm0 + qm * 32 + fm * 16 + quad * 4;
        float xv[4];
#pragma unroll
        for (int r = 0; r < 4; ++r) xv[r] = x[(size_t)(rb + r) * TT + t];
#pragma unroll
        for (int fn = 0; fn < 4; ++fn) {
            int col = cn0 + fn * 16 + lrow;
            float wx = Whx[col], bb = bh[col];
            int cbyte = (fn * 16 + lrow) * 2;
#pragma unroll
            for (int r = 0; r < 4; ++r) {
                int row_l = fm * 16 + quad * 4 + r;
                float z = acc[fm][fn][r] + wx * xv[r] + bb;
                *(bf16*)((char*)Lw + row_l * 128 +
                         (cbyte ^ ((row_l & 7) << 4))) = (bf16)tanhf(z);
            }
        }
    }
    __syncthreads();
    // read own wave's tile in frag-slot order; 16B coalesced global stores.
#pragma unroll
    for (int fm = 0; fm < 2; ++fm) {
#pragma unroll
        for (int kc = 0; kc < 2; ++kc) {
            int row_l = fm * 16 + lrow;
            int cb    = (kc * 64 + quad * 16) ^ ((row_l & 7) << 4);
            bf16x8 v = *(const bf16x8*)((const char*)Lw + row_l * 128 + cb);
            size_t sub = (size_t)(m16w + fm) * 64 + (cn0 >> 5) + kc;
            *(bf16x8*)(Sw + (sub * 64 + lane) * 8) = v;
        }
    }
}

// ---------------------------------------------------------------------------
// out[b,c] = sum_h Why[h,c] * S[b,h] + bp[c]   (S frag-major)
// ---------------------------------------------------------------------------
__global__ void out_proj(const bf16* __restrict__ S,
                         const float* __restrict__ Why,   // [H, C]
                         const float* __restrict__ bp,    // [C]
                         float* __restrict__ out) {       // [B, C]
    int b = blockIdx.x, tid = threadIdx.x;
    int h0 = tid * 8;                                     // 256*8 = H exactly
    size_t sub  = (size_t)(b >> 4) * 64 + (h0 >> 5);
    size_t slot = (size_t)(b & 15) | (size_t)(((h0 >> 3) & 3) << 4);
    bf16x8 v = *(const bf16x8*)(S + (sub * 64 + slot) * 8);
    float p[NC];
#pragma unroll
    for (int c = 0; c < NC; ++c) p[c] = 0.f;
#pragma unroll
    for (int j = 0; j < 8; ++j) {
        float s = (float)v[j];
        const float* wr = Why + (size_t)(h0 + j) * NC;
#pragma unroll
        for (int c = 0; c < NC; ++c) p[c] += s * wr[c];
    }
    __shared__ float red[256 * NC];
#pragma unroll
    for (int c = 0; c < NC; ++c) red[tid * NC + c] = p[c];
    __syncthreads();
    for (int s = 128; s > 0; s >>= 1) {
        if (tid < s)
#pragma unroll
            for (int c = 0; c < NC; ++c) red[tid * NC + c] += red[(tid + s) * NC + c];
        __syncthreads();
    }
    if (tid < NC) out[(size_t)b * NC + tid] = red[tid] + bp[tid];
}

// ---------------------------------------------------------------------------
extern "C" void kernel_launch(void* const* d_in, const int* in_sizes, int n_in,
                              void* d_out, int out_size, void* d_ws, size_t ws_size,
                              hipStream_t stream) {
    const float* x   = (const float*)d_in[0];   // [B, T]
    const float* Whx = (const float*)d_in[1];   // [H, 1]
    const float* Whh = (const float*)d_in[2];   // [H, H]
    const float* Why = (const float*)d_in[3];   // [H, C]
    const float* bh  = (const float*)d_in[4];   // [H, 1]
    const float* bp  = (const float*)d_in[5];   // [C, 1]
    float* out = (float*)d_out;

    // workspace: Wshuf (8 MB) | S0 (8 MB) | S1 (8 MB)   (all frag-major)
    bf16* Wshuf = (bf16*)d_ws;
    bf16* S0 = (bf16*)((char*)d_ws + (size_t)8 * 1024 * 1024);
    bf16* S1 = (bf16*)((char*)d_ws + (size_t)16 * 1024 * 1024);

    hipLaunchKernelGGL(w_shuffle_kernel, dim3((H * H / 8) / 256), dim3(256),
                       0, stream, Whh, Wshuf);

    // t = 0 writes S1; step t reads (t&1 ? S1 : S0), writes the other.
    hipLaunchKernelGGL(rnn_init, dim3(BB), dim3(256), 0, stream, x, Whx, bh, S1);

    for (int t = 1; t < TT; ++t) {
        const bf16* Srd = (t & 1) ? S1 : S0;
        bf16*       Swr = (t & 1) ? S0 : S1;
        hipLaunchKernelGGL(rnn_step, dim3(256), dim3(512), 0, stream,
                           x, Whx, bh, Wshuf, Srd, Swr, t);
    }

    // t=63 (odd) wrote S0
    hipLaunchKernelGGL(out_proj, dim3(BB), dim3(256), 0, stream, S0, Why, bp, out);
}

// Round 4
// 1645.575 us; speedup vs baseline: 2.9121x; 1.0607x over previous
//
#include <hip/hip_runtime.h>
#include <cstdint>
#include <cstddef>
#include <cmath>

#define H  2048
#define BB 2048   // batch
#define TT 64     // time steps
#define NC 10     // classes

typedef __bf16 bf16;
typedef bf16  bf16x8 __attribute__((ext_vector_type(8)));
typedef float f32x4  __attribute__((ext_vector_type(4)));

// ---------------------------------------------------------------------------
// async global->LDS, 16B per lane. LDS dest is wave-uniform base + lane*16;
// global source is per-lane.
// ---------------------------------------------------------------------------
__device__ __forceinline__ void load_lds16(const void* g, void* l) {
    __builtin_amdgcn_global_load_lds(
        (__attribute__((address_space(1))) void*)(void*)g,
        (__attribute__((address_space(3))) void*)l,
        16, 0, 0);
}

// ---------------------------------------------------------------------------
// FRAG-MAJOR layout (W_hh and S, since R12).
// For a matrix [R rows][H k-cols] (bf16):
//   subtile (r16, k32) = 16 rows x 32 k = 1024 B at id = r16*(H/32) + k32.
//   lane-slot l (16 B) holds M[r16*16 + (l&15)][k32*32 + (l>>4)*8 .. +8]
// = exactly the v_mfma_f32_16x16x32_bf16 A/B fragment, so a wave's frag load
// is ONE coalesced 1 KB segment: base + id*512 + lane*8 (bf16 elems).
// ---------------------------------------------------------------------------
__global__ void w_shuffle_kernel(const float* __restrict__ Whh,
                                 bf16* __restrict__ Wshuf) {
    int tid = blockIdx.x * blockDim.x + threadIdx.x;   // 0 .. H*H/8-1
    int sub = tid >> 6;          // subtile id
    int l   = tid & 63;          // dest lane slot
    int n16 = sub >> 6;          // 0..127
    int k32 = sub & 63;          // 0..63
    int n = n16 * 16 + (l & 15);
    int k = k32 * 32 + (l >> 4) * 8;
    const float* src = Whh + (size_t)n * H + k;
    bf16x8 o;
#pragma unroll
    for (int j = 0; j < 8; ++j) o[j] = (bf16)src[j];
    *(bf16x8*)(Wshuf + (size_t)tid * 8) = o;
}

// ---------------------------------------------------------------------------
// t = 0: S[b,i] = tanh(Whx[i]*x[b,0] + bh[i]), written FRAG-MAJOR.
// ---------------------------------------------------------------------------
__global__ void rnn_init(const float* __restrict__ x,     // [B, T]
                         const float* __restrict__ Whx,   // [H]
                         const float* __restrict__ bh,    // [H]
                         bf16* __restrict__ S) {          // frag-major
    int b  = blockIdx.x;
    int i0 = threadIdx.x * 8;
    float xv = x[(size_t)b * TT];
    bf16x8 o;
#pragma unroll
    for (int j = 0; j < 8; ++j)
        o[j] = (bf16)tanhf(Whx[i0 + j] * xv + bh[i0 + j]);
    size_t sub  = (size_t)(b >> 4) * 64 + (i0 >> 5);
    size_t slot = (size_t)(b & 15) | (size_t)(((i0 >> 3) & 3) << 4);
    *(bf16x8*)(S + (sub * 64 + slot) * 8) = o;
}

// ---------------------------------------------------------------------------
// One RNN time step, Round-14 "counted-vmcnt ring pipeline" (T3+T4 port):
//   Sw[b,i] = tanh( sum_k Sr[b,k]*W[i,k] + Whx[i]*x[b,t] + bh[i] )
//
// R13 post-mortem: per-pipe times SUMMED (27us ~= 7 VMEM + 10 LDS + 8 MFMA +
// epilogue) because every __syncthreads drains vmcnt(0), killing prefetch.
// Fix (m201 pattern): raw s_barrier + counted s_waitcnt vmcnt(N), N never 0
// in the main loop, 3-phase-deep prefetch.
//
//   - 32 phases x 2 k32-chunks. 4-slot LDS ring (4 x 16 KB); slot p&3 holds
//     phase p's B (2 chunks x 8 subtiles x 1 KB). Stage of phase p+3 issues
//     AFTER barrier(p) -> all waves finished reading that slot (overwrite-
//     safe); its data is consumed 3 phases (~3000 cy) later.
//   - Per wave per phase: 2 global_load_lds (B) + 4 reg loads (A, depth-4
//     named ring, static indices) = 6 VMEM ops, pinned inside
//     sched_barrier(0) fences so issue order/count is deterministic.
//   - Phase protocol: s_waitcnt vmcnt(12) [= 2 younger phases in flight ->
//     own phase's ops complete] ; s_barrier [all waves' stages landed] ;
//     issue phase p+3 ; compute phase p (ds_read B + MFMA; compiler manages
//     lgkmcnt + its own precise vmcnt for the A regs). Tail peels to
//     vmcnt(12/6/0).
//   - Geometry unchanged from R13: 128x128 tile, grid 256 = 1 block/CU,
//     8 waves, wave 32(m) x 64(n); XCD-aware m-mapping; accumulation order
//     identical -> bit-identical numerics.
// ---------------------------------------------------------------------------
#define PH_WAIT(NSTR) asm volatile("s_waitcnt vmcnt(" NSTR ")" ::: "memory")
#define SBAR0()       __builtin_amdgcn_sched_barrier(0)

__launch_bounds__(512, 2)
__global__ void rnn_step(const float* __restrict__ x,     // [B, T]
                         const float* __restrict__ Whx,   // [H]
                         const float* __restrict__ bh,    // [H]
                         const bf16*  __restrict__ Wshuf, // frag-major W_hh
                         const bf16*  __restrict__ Sr,    // frag-major S read
                         bf16* __restrict__ Sw,           // frag-major S write
                         int t) {
    __shared__ __align__(16) char Bs[4][16384];   // 4-slot B ring, 64 KB

    const int tid  = threadIdx.x;
    const int w    = tid >> 6;          // wave 0..7
    const int lane = tid & 63;
    const int lrow = lane & 15;
    const int quad = lane >> 4;

    // XCD-aware: XCD owns batch rows -> S produced AND consumed in-XCD (L2).
    const int xcd = blockIdx.x & 7;
    const int loc = blockIdx.x >> 3;               // 0..31
    const int bm0 = (xcd * 2 + (loc & 1)) * 128;   // batch-row tile origin
    const int bn0 = (loc >> 1) * 128;              // hidden-col tile origin

    const int qm   = w & 3;                        // 4 m-groups x 32 rows
    const int qn   = w >> 2;                       // 2 n-groups x 64 cols
    const int m16w = (bm0 >> 4) + qm * 2;          // wave's first m16 subtile
    const int cn0  = bn0 + qn * 64;                // wave's first col
    const int n16b = bn0 >> 4;                     // block's first n16 subtile

    const bf16* pA  = Sr + (size_t)lane * 8;
    const bf16* pSt = Wshuf + ((size_t)(n16b + w) * 64) * 512 + (size_t)lane * 8;

    f32x4 acc[2][4];
#pragma unroll
    for (int i = 0; i < 2; ++i)
#pragma unroll
        for (int j = 0; j < 4; ++j) acc[i][j] = (f32x4){0.f, 0.f, 0.f, 0.f};

    // A register ring: 4 phase-slots x 2 chunks x 2 fm (all indices static).
    bf16x8 Ar[4][2][2];

    // ---- issue section for phase pp into ring/slot RI (6 VMEM ops) ----
#define ISSUE(RI, pp)                                                        \
    {                                                                        \
        _Pragma("unroll")                                                    \
        for (int j = 0; j < 2; ++j) {                                        \
            load_lds16(pSt + (size_t)(2 * (pp) + j) * 512,                   \
                       &Bs[RI][(j * 8 + w) * 1024]);                         \
            _Pragma("unroll")                                                \
            for (int fm = 0; fm < 2; ++fm)                                   \
                Ar[RI][j][fm] = *(const bf16x8*)(pA +                        \
                    (size_t)((m16w + fm) * 64 + 2 * (pp) + j) * 512);        \
        }                                                                    \
    }

    // ---- compute section for phase p using ring/slot RI ----
#define COMPUTE(RI)                                                          \
    {                                                                        \
        _Pragma("unroll")                                                    \
        for (int j = 0; j < 2; ++j) {                                        \
            bf16x8 Bf[4];                                                    \
            _Pragma("unroll")                                                \
            for (int fn = 0; fn < 4; ++fn)                                   \
                Bf[fn] = *(const bf16x8*)&Bs[RI]                             \
                    [(j * 8 + qn * 4 + fn) * 1024 + lane * 16];              \
            _Pragma("unroll")                                                \
            for (int fm = 0; fm < 2; ++fm)                                   \
                _Pragma("unroll")                                            \
                for (int fn = 0; fn < 4; ++fn)                               \
                    acc[fm][fn] = __builtin_amdgcn_mfma_f32_16x16x32_bf16(   \
                        Ar[RI][j][fm], Bf[fn], acc[fm][fn], 0, 0, 0);        \
        }                                                                    \
    }

#define PHASE(RI, RN, p, WNSTR, DOISS)                                       \
    {                                                                        \
        PH_WAIT(WNSTR);                                                      \
        SBAR0();                                                             \
        __builtin_amdgcn_s_barrier();                                        \
        SBAR0();                                                             \
        if (DOISS) ISSUE(RN, (p) + 3);                                       \
        SBAR0();                                                             \
        COMPUTE(RI);                                                         \
    }

    // prologue: issue phases 0,1,2 (sections kept in order by fences)
    ISSUE(0, 0); SBAR0();
    ISSUE(1, 1); SBAR0();
    ISSUE(2, 2); SBAR0();

    // main loop: phases 0..27 (7 macro-iters x 4), steady wait = 12
#pragma unroll 1
    for (int q = 0; q < 7; ++q) {
        int p = 4 * q;
        PHASE(0, 3, p + 0, "12", true);
        PHASE(1, 0, p + 1, "12", true);
        PHASE(2, 1, p + 2, "12", true);
        PHASE(3, 2, p + 3, "12", true);
    }
    // peeled tail: phases 28..31
    PHASE(0, 3, 28, "12", true);    // issues phase 31
    PHASE(1, 0, 29, "12", false);
    PHASE(2, 1, 30, "6",  false);
    PHASE(3, 2, 31, "0",  false);

#undef PHASE
#undef COMPUTE
#undef ISSUE

    // ---- epilogue: z += Whx*x + bh; tanh; transpose to frag-major Sw ----
    // acc layout (16x16x32): col = lane&15, row = quad*4 + reg [m89-verified]
    // Transpose region = bytes 0..32K (slots 0,1); any wave still in phase 31
    // reads slot 3 (48..64K) -> disjoint, safe.
    bf16* Lw = (bf16*)&Bs[0][0] + (size_t)w * 2048;  // 32 rows x 128 B, swz
#pragma unroll
    for (int fm = 0; fm < 2; ++fm) {
        int rb = bm0 + qm * 32 + fm * 16 + quad * 4;
        float xv[4];
#pragma unroll
        for (int r = 0; r < 4; ++r) xv[r] = x[(size_t)(rb + r) * TT + t];
#pragma unroll
        for (int fn = 0; fn < 4; ++fn) {
            int col = cn0 + fn * 16 + lrow;
            float wx = Whx[col], bb = bh[col];
            int cbyte = (fn * 16 + lrow) * 2;
#pragma unroll
            for (int r = 0; r < 4; ++r) {
                int row_l = fm * 16 + quad * 4 + r;
                float z = acc[fm][fn][r] + wx * xv[r] + bb;
                *(bf16*)((char*)Lw + row_l * 128 +
                         (cbyte ^ ((row_l & 7) << 4))) = (bf16)tanhf(z);
            }
        }
    }
    __syncthreads();
    // read own wave's tile in frag-slot order; 16B coalesced global stores.
#pragma unroll
    for (int fm = 0; fm < 2; ++fm) {
#pragma unroll
        for (int kc = 0; kc < 2; ++kc) {
            int row_l = fm * 16 + lrow;
            int cb    = (kc * 64 + quad * 16) ^ ((row_l & 7) << 4);
            bf16x8 v = *(const bf16x8*)((const char*)Lw + row_l * 128 + cb);
            size_t sub = (size_t)(m16w + fm) * 64 + (cn0 >> 5) + kc;
            *(bf16x8*)(Sw + (sub * 64 + lane) * 8) = v;
        }
    }
}

// ---------------------------------------------------------------------------
// out[b,c] = sum_h Why[h,c] * S[b,h] + bp[c]   (S frag-major)
// ---------------------------------------------------------------------------
__global__ void out_proj(const bf16* __restrict__ S,
                         const float* __restrict__ Why,   // [H, C]
                         const float* __restrict__ bp,    // [C]
                         float* __restrict__ out) {       // [B, C]
    int b = blockIdx.x, tid = threadIdx.x;
    int h0 = tid * 8;                                     // 256*8 = H exactly
    size_t sub  = (size_t)(b >> 4) * 64 + (h0 >> 5);
    size_t slot = (size_t)(b & 15) | (size_t)(((h0 >> 3) & 3) << 4);
    bf16x8 v = *(const bf16x8*)(S + (sub * 64 + slot) * 8);
    float p[NC];
#pragma unroll
    for (int c = 0; c < NC; ++c) p[c] = 0.f;
#pragma unroll
    for (int j = 0; j < 8; ++j) {
        float s = (float)v[j];
        const float* wr = Why + (size_t)(h0 + j) * NC;
#pragma unroll
        for (int c = 0; c < NC; ++c) p[c] += s * wr[c];
    }
    __shared__ float red[256 * NC];
#pragma unroll
    for (int c = 0; c < NC; ++c) red[tid * NC + c] = p[c];
    __syncthreads();
    for (int s = 128; s > 0; s >>= 1) {
        if (tid < s)
#pragma unroll
            for (int c = 0; c < NC; ++c) red[tid * NC + c] += red[(tid + s) * NC + c];
        __syncthreads();
    }
    if (tid < NC) out[(size_t)b * NC + tid] = red[tid] + bp[tid];
}

// ---------------------------------------------------------------------------
extern "C" void kernel_launch(void* const* d_in, const int* in_sizes, int n_in,
                              void* d_out, int out_size, void* d_ws, size_t ws_size,
                              hipStream_t stream) {
    const float* x   = (const float*)d_in[0];   // [B, T]
    const float* Whx = (const float*)d_in[1];   // [H, 1]
    const float* Whh = (const float*)d_in[2];   // [H, H]
    const float* Why = (const float*)d_in[3];   // [H, C]
    const float* bh  = (const float*)d_in[4];   // [H, 1]
    const float* bp  = (const float*)d_in[5];   // [C, 1]
    float* out = (float*)d_out;

    // workspace: Wshuf (8 MB) | S0 (8 MB) | S1 (8 MB)   (all frag-major)
    bf16* Wshuf = (bf16*)d_ws;
    bf16* S0 = (bf16*)((char*)d_ws + (size_t)8 * 1024 * 1024);
    bf16* S1 = (bf16*)((char*)d_ws + (size_t)16 * 1024 * 1024);

    hipLaunchKernelGGL(w_shuffle_kernel, dim3((H * H / 8) / 256), dim3(256),
                       0, stream, Whh, Wshuf);

    // t = 0 writes S1; step t reads (t&1 ? S1 : S0), writes the other.
    hipLaunchKernelGGL(rnn_init, dim3(BB), dim3(256), 0, stream, x, Whx, bh, S1);

    for (int t = 1; t < TT; ++t) {
        const bf16* Srd = (t & 1) ? S1 : S0;
        bf16*       Swr = (t & 1) ? S0 : S1;
        hipLaunchKernelGGL(rnn_step, dim3(256), dim3(512), 0, stream,
                           x, Whx, bh, Wshuf, Srd, Swr, t);
    }

    // t=63 (odd) wrote S0
    hipLaunchKernelGGL(out_proj, dim3(BB), dim3(256), 0, stream, S0, Why, bp, out);
}

// Round 5
// 1543.729 us; speedup vs baseline: 3.1043x; 1.0660x over previous
//
#include <hip/hip_runtime.h>
#include <cstdint>
#include <cstddef>
#include <cmath>

#define H  2048
#define BB 2048   // batch
#define TT 64     // time steps
#define NC 10     // classes

typedef __bf16 bf16;
typedef bf16  bf16x8 __attribute__((ext_vector_type(8)));
typedef float f32x4  __attribute__((ext_vector_type(4)));

// ---------------------------------------------------------------------------
// async global->LDS, 16B per lane. LDS dest is wave-uniform base + lane*16;
// global source is per-lane.
// ---------------------------------------------------------------------------
__device__ __forceinline__ void load_lds16(const void* g, void* l) {
    __builtin_amdgcn_global_load_lds(
        (__attribute__((address_space(1))) void*)(void*)g,
        (__attribute__((address_space(3))) void*)l,
        16, 0, 0);
}

// ---------------------------------------------------------------------------
// FRAG-MAJOR layout (W_hh and S, since R12).
// For a matrix [R rows][H k-cols] (bf16):
//   subtile (r16, k32) = 16 rows x 32 k = 1024 B at id = r16*(H/32) + k32.
//   lane-slot l (16 B) holds M[r16*16 + (l&15)][k32*32 + (l>>4)*8 .. +8]
// = exactly the v_mfma_f32_16x16x32_bf16 A/B fragment, so a wave's frag load
// is ONE coalesced 1 KB segment: base + id*512 + lane*8 (bf16 elems).
// ---------------------------------------------------------------------------
__global__ void w_shuffle_kernel(const float* __restrict__ Whh,
                                 bf16* __restrict__ Wshuf) {
    int tid = blockIdx.x * blockDim.x + threadIdx.x;   // 0 .. H*H/8-1
    int sub = tid >> 6;          // subtile id
    int l   = tid & 63;          // dest lane slot
    int n16 = sub >> 6;          // 0..127
    int k32 = sub & 63;          // 0..63
    int n = n16 * 16 + (l & 15);
    int k = k32 * 32 + (l >> 4) * 8;
    const float* src = Whh + (size_t)n * H + k;
    bf16x8 o;
#pragma unroll
    for (int j = 0; j < 8; ++j) o[j] = (bf16)src[j];
    *(bf16x8*)(Wshuf + (size_t)tid * 8) = o;
}

// ---------------------------------------------------------------------------
// t = 0: S[b,i] = tanh(Whx[i]*x[b,0] + bh[i]), written FRAG-MAJOR.
// ---------------------------------------------------------------------------
__global__ void rnn_init(const float* __restrict__ x,     // [B, T]
                         const float* __restrict__ Whx,   // [H]
                         const float* __restrict__ bh,    // [H]
                         bf16* __restrict__ S) {          // frag-major
    int b  = blockIdx.x;
    int i0 = threadIdx.x * 8;
    float xv = x[(size_t)b * TT];
    bf16x8 o;
#pragma unroll
    for (int j = 0; j < 8; ++j)
        o[j] = (bf16)tanhf(Whx[i0 + j] * xv + bh[i0 + j]);
    size_t sub  = (size_t)(b >> 4) * 64 + (i0 >> 5);
    size_t slot = (size_t)(b & 15) | (size_t)(((i0 >> 3) & 3) << 4);
    *(bf16x8*)(S + (sub * 64 + slot) * 8) = o;
}

// ---------------------------------------------------------------------------
// One RNN time step, Round-15 "both-operand LDS ring + setprio + XCD-owns-n":
//   Sw[b,i] = tanh( sum_k Sr[b,k]*W[i,k] + Whx[i]*x[b,t] + bh[i] )
//
// R14 post-mortem: pipes still summed (~25us vs max-pipe 11us) because
// (a) A's 2x reg-direct duplication made VMEM the fattest pipe (48 KB/phase
// = 857cy > MFMA 620cy), and (b) the per-phase barrier convoys all 8 waves
// into the same pipe at once with nothing arbitrating toward MFMA.
//
// Fixes:
//   - BOTH operands staged via global_load_lds: per-phase VMEM = unique
//     32 KB (571cy) < MFMA (620cy). LDS-read 48 KB/phase on the 256 B/cy
//     pipe, conflict-free (linear frag-slot ds_read_b128).
//   - T5: s_setprio(1) around each MFMA cluster — the phase-split schedule
//     gives the CU scheduler wave role-diversity to arbitrate (m218b regime).
//   - XCD-owns-n: XCD x owns hidden-cols [x*256, x*256+256). Its W panel is
//     1 MB -> L2-RESIDENT across all 63 steps (B stage = guaranteed L2 hit).
//     S streams cross-XCD but is prefetched 3 phases deep.
//   - 4-slot LDS ring (4 x 32 KB = 128 KB), phase = 64 k. Per wave per phase
//     exactly 4 gload_lds (2 A + 2 B segs, 1 KB each). Steady-state wait =
//     vmcnt(8) (2 younger phases in flight), never 0 in-loop; tail 8/4/0.
//   - Slot overwrite safety: issue(p+3) targets slot (p-1)&3, whose readers
//     all passed barrier(p). Raw s_barrier only (no drain).
//   - Accumulation order (k ascending, fm->fn) and epilogue identical to
//     R14 -> bit-identical numerics.
// ---------------------------------------------------------------------------
#define PH_WAIT(NSTR) asm volatile("s_waitcnt vmcnt(" NSTR ")" ::: "memory")
#define SBAR0()       __builtin_amdgcn_sched_barrier(0)

__launch_bounds__(512)
__global__ void rnn_step(const float* __restrict__ x,     // [B, T]
                         const float* __restrict__ Whx,   // [H]
                         const float* __restrict__ bh,    // [H]
                         const bf16*  __restrict__ Wshuf, // frag-major W_hh
                         const bf16*  __restrict__ Sr,    // frag-major S read
                         bf16* __restrict__ Sw,           // frag-major S write
                         int t) {
    // ring slot = 32 segs x 1 KB: segs [j*16 + 0..7] = A m16 0..7 (chunk j),
    //                             segs [j*16 + 8..15] = B n16 0..7 (chunk j)
    __shared__ __align__(16) char Ls[4][32768];   // 128 KB -> 1 block/CU

    const int tid  = threadIdx.x;
    const int w    = tid >> 6;          // wave 0..7
    const int lane = tid & 63;
    const int lrow = lane & 15;
    const int quad = lane >> 4;

    // XCD-owns-n mapping: XCD x covers n-cols [x*256, x*256+256).
    const int xcd = blockIdx.x & 7;
    const int loc = blockIdx.x >> 3;               // 0..31
    const int bm0 = (loc >> 1) * 128;              // batch-row tile origin
    const int bn0 = xcd * 256 + (loc & 1) * 128;   // hidden-col tile origin

    const int qm   = w & 3;                        // 4 m-groups x 32 rows
    const int qn   = w >> 2;                       // 2 n-groups x 64 cols
    const int m16w = (bm0 >> 4) + qm * 2;          // wave's first m16 subtile
    const int cn0  = bn0 + qn * 64;                // wave's first col

    // staging sources (per wave): wave w owns A subtile m16=(bm0>>4)+w and
    // B subtile n16=(bn0>>4)+w; 1 KB contiguous per k32, per-lane +lane*16B.
    const char* srcA = (const char*)Sr +
        ((size_t)((bm0 >> 4) + w) * 64) * 1024 + (size_t)lane * 16;
    const char* srcB = (const char*)Wshuf +
        ((size_t)((bn0 >> 4) + w) * 64) * 1024 + (size_t)lane * 16;

    f32x4 acc[2][4];
#pragma unroll
    for (int i = 0; i < 2; ++i)
#pragma unroll
        for (int j = 0; j < 4; ++j) acc[i][j] = (f32x4){0.f, 0.f, 0.f, 0.f};

    // ---- issue section for phase pp into ring slot RI (4 VMEM ops) ----
#define ISSUE(RI, pp)                                                        \
    {                                                                        \
        _Pragma("unroll")                                                    \
        for (int j = 0; j < 2; ++j) {                                        \
            load_lds16(srcA + (size_t)(2 * (pp) + j) * 1024,                 \
                       &Ls[RI][(j * 16 + w) * 1024]);                        \
            load_lds16(srcB + (size_t)(2 * (pp) + j) * 1024,                 \
                       &Ls[RI][(j * 16 + 8 + w) * 1024]);                    \
        }                                                                    \
    }

    // ---- compute section for phase p using ring slot RI ----
#define COMPUTE(RI)                                                          \
    {                                                                        \
        _Pragma("unroll")                                                    \
        for (int j = 0; j < 2; ++j) {                                        \
            bf16x8 Af[2], Bf[4];                                             \
            _Pragma("unroll")                                                \
            for (int fm = 0; fm < 2; ++fm)                                   \
                Af[fm] = *(const bf16x8*)&Ls[RI]                             \
                    [(j * 16 + qm * 2 + fm) * 1024 + lane * 16];             \
            _Pragma("unroll")                                                \
            for (int fn = 0; fn < 4; ++fn)                                   \
                Bf[fn] = *(const bf16x8*)&Ls[RI]                             \
                    [(j * 16 + 8 + qn * 4 + fn) * 1024 + lane * 16];         \
            __builtin_amdgcn_s_setprio(1);                                   \
            _Pragma("unroll")                                                \
            for (int fm = 0; fm < 2; ++fm)                                   \
                _Pragma("unroll")                                            \
                for (int fn = 0; fn < 4; ++fn)                               \
                    acc[fm][fn] = __builtin_amdgcn_mfma_f32_16x16x32_bf16(   \
                        Af[fm], Bf[fn], acc[fm][fn], 0, 0, 0);               \
            __builtin_amdgcn_s_setprio(0);                                   \
        }                                                                    \
    }

#define PHASE(RI, RN, p, WNSTR, DOISS)                                       \
    {                                                                        \
        PH_WAIT(WNSTR);                                                      \
        SBAR0();                                                             \
        __builtin_amdgcn_s_barrier();                                        \
        SBAR0();                                                             \
        if (DOISS) ISSUE(RN, (p) + 3);                                       \
        SBAR0();                                                             \
        COMPUTE(RI);                                                         \
    }

    // prologue: issue phases 0,1,2 into slots 0,1,2 (order pinned)
    ISSUE(0, 0); SBAR0();
    ISSUE(1, 1); SBAR0();
    ISSUE(2, 2); SBAR0();

    // main loop: phases 0..27 (7 macro-iters x 4), steady wait = 8
#pragma unroll 1
    for (int q = 0; q < 7; ++q) {
        int p = 4 * q;
        PHASE(0, 3, p + 0, "8", true);
        PHASE(1, 0, p + 1, "8", true);
        PHASE(2, 1, p + 2, "8", true);
        PHASE(3, 2, p + 3, "8", true);
    }
    // peeled tail: phases 28..31
    PHASE(0, 3, 28, "8", true);    // issues phase 31
    PHASE(1, 0, 29, "8", false);
    PHASE(2, 1, 30, "4", false);
    PHASE(3, 2, 31, "0", false);

#undef PHASE
#undef COMPUTE
#undef ISSUE

    // ---- epilogue: z += Whx*x + bh; tanh; transpose to frag-major Sw ----
    // acc layout (16x16x32): col = lane&15, row = quad*4 + reg [m89-verified]
    // Transpose region = bytes 0..32K (slot 0, phase-28 data, consumed by all
    // waves before barrier(29)); stragglers compute phase 31 in slot 3 ->
    // disjoint, safe without a drain barrier.
    bf16* Lw = (bf16*)&Ls[0][0] + (size_t)w * 2048;  // 32 rows x 128 B, swz
#pragma unroll
    for (int fm = 0; fm < 2; ++fm) {
        int rb = bm0 + qm * 32 + fm * 16 + quad * 4;
        float xv[4];
#pragma unroll
        for (int r = 0; r < 4; ++r) xv[r] = x[(size_t)(rb + r) * TT + t];
#pragma unroll
        for (int fn = 0; fn < 4; ++fn) {
            int col = cn0 + fn * 16 + lrow;
            float wx = Whx[col], bb = bh[col];
            int cbyte = (fn * 16 + lrow) * 2;
#pragma unroll
            for (int r = 0; r < 4; ++r) {
                int row_l = fm * 16 + quad * 4 + r;
                float z = acc[fm][fn][r] + wx * xv[r] + bb;
                *(bf16*)((char*)Lw + row_l * 128 +
                         (cbyte ^ ((row_l & 7) << 4))) = (bf16)tanhf(z);
            }
        }
    }
    __syncthreads();
    // read own wave's tile in frag-slot order; 16B coalesced global stores.
#pragma unroll
    for (int fm = 0; fm < 2; ++fm) {
#pragma unroll
        for (int kc = 0; kc < 2; ++kc) {
            int row_l = fm * 16 + lrow;
            int cb    = (kc * 64 + quad * 16) ^ ((row_l & 7) << 4);
            bf16x8 v = *(const bf16x8*)((const char*)Lw + row_l * 128 + cb);
            size_t sub = (size_t)(m16w + fm) * 64 + (cn0 >> 5) + kc;
            *(bf16x8*)(Sw + (sub * 64 + lane) * 8) = v;
        }
    }
}

// ---------------------------------------------------------------------------
// out[b,c] = sum_h Why[h,c] * S[b,h] + bp[c]   (S frag-major)
// ---------------------------------------------------------------------------
__global__ void out_proj(const bf16* __restrict__ S,
                         const float* __restrict__ Why,   // [H, C]
                         const float* __restrict__ bp,    // [C]
                         float* __restrict__ out) {       // [B, C]
    int b = blockIdx.x, tid = threadIdx.x;
    int h0 = tid * 8;                                     // 256*8 = H exactly
    size_t sub  = (size_t)(b >> 4) * 64 + (h0 >> 5);
    size_t slot = (size_t)(b & 15) | (size_t)(((h0 >> 3) & 3) << 4);
    bf16x8 v = *(const bf16x8*)(S + (sub * 64 + slot) * 8);
    float p[NC];
#pragma unroll
    for (int c = 0; c < NC; ++c) p[c] = 0.f;
#pragma unroll
    for (int j = 0; j < 8; ++j) {
        float s = (float)v[j];
        const float* wr = Why + (size_t)(h0 + j) * NC;
#pragma unroll
        for (int c = 0; c < NC; ++c) p[c] += s * wr[c];
    }
    __shared__ float red[256 * NC];
#pragma unroll
    for (int c = 0; c < NC; ++c) red[tid * NC + c] = p[c];
    __syncthreads();
    for (int s = 128; s > 0; s >>= 1) {
        if (tid < s)
#pragma unroll
            for (int c = 0; c < NC; ++c) red[tid * NC + c] += red[(tid + s) * NC + c];
        __syncthreads();
    }
    if (tid < NC) out[(size_t)b * NC + tid] = red[tid] + bp[tid];
}

// ---------------------------------------------------------------------------
extern "C" void kernel_launch(void* const* d_in, const int* in_sizes, int n_in,
                              void* d_out, int out_size, void* d_ws, size_t ws_size,
                              hipStream_t stream) {
    const float* x   = (const float*)d_in[0];   // [B, T]
    const float* Whx = (const float*)d_in[1];   // [H, 1]
    const float* Whh = (const float*)d_in[2];   // [H, H]
    const float* Why = (const float*)d_in[3];   // [H, C]
    const float* bh  = (const float*)d_in[4];   // [H, 1]
    const float* bp  = (const float*)d_in[5];   // [C, 1]
    float* out = (float*)d_out;

    // workspace: Wshuf (8 MB) | S0 (8 MB) | S1 (8 MB)   (all frag-major)
    bf16* Wshuf = (bf16*)d_ws;
    bf16* S0 = (bf16*)((char*)d_ws + (size_t)8 * 1024 * 1024);
    bf16* S1 = (bf16*)((char*)d_ws + (size_t)16 * 1024 * 1024);

    hipLaunchKernelGGL(w_shuffle_kernel, dim3((H * H / 8) / 256), dim3(256),
                       0, stream, Whh, Wshuf);

    // t = 0 writes S1; step t reads (t&1 ? S1 : S0), writes the other.
    hipLaunchKernelGGL(rnn_init, dim3(BB), dim3(256), 0, stream, x, Whx, bh, S1);

    for (int t = 1; t < TT; ++t) {
        const bf16* Srd = (t & 1) ? S1 : S0;
        bf16*       Swr = (t & 1) ? S0 : S1;
        hipLaunchKernelGGL(rnn_step, dim3(256), dim3(512), 0, stream,
                           x, Whx, bh, Wshuf, Srd, Swr, t);
    }

    // t=63 (odd) wrote S0
    hipLaunchKernelGGL(out_proj, dim3(BB), dim3(256), 0, stream, S0, Why, bp, out);
}